// Round 1
// baseline (80.877 us; speedup 1.0000x reference)
//
#include <hip/hip_runtime.h>

// HilbertSimulator — closed-form reduction.
//
// Reference circuit: RY(x_i) then RY(w_i) per qubit on |0000> (RY compose:
// angle theta_i = x_i + w_i -> product state), then 4 CNOTs (a GF(2)-linear
// permutation), then probs @ Z. Z-expectation of an XOR-of-bits factorizes
// over a product distribution into a product of cos(2*theta_i):
//   d_i = cos(2*(x_i + w_i))
//   out = ( d1*d2*d3, d0*d1, d0*d1*d2, d0*d1*d2*d3 )
// Derivation/verification in session notes; matches reference bit/qubit
// conventions (qubit i <-> bit (3-i), new[k] = old[perm[k]]).

__global__ __launch_bounds__(256) void HilbertSimulator_12275016532163_kernel(
    const float4* __restrict__ x,   // (BATCH, 4) as float4
    const float*  __restrict__ w,   // (1, 4)
    float4*       __restrict__ out, // (BATCH, 4) as float4
    int batch)
{
    const int b = blockIdx.x * blockDim.x + threadIdx.x;
    if (b >= batch) return;

    // Uniform weights -> scalar loads (broadcast via constant cache).
    const float w0 = w[0], w1 = w[1], w2 = w[2], w3 = w[3];

    const float4 xv = x[b];   // coalesced 16 B/lane

    const float d0 = __cosf(2.0f * (xv.x + w0));
    const float d1 = __cosf(2.0f * (xv.y + w1));
    const float d2 = __cosf(2.0f * (xv.z + w2));
    const float d3 = __cosf(2.0f * (xv.w + w3));

    float4 o;
    o.y = d0 * d1;           // <Z1> = d0*d1
    o.x = d1 * d2 * d3;      // <Z0> = d1*d2*d3
    o.z = o.y * d2;          // <Z2> = d0*d1*d2
    o.w = o.z * d3;          // <Z3> = d0*d1*d2*d3

    out[b] = o;              // coalesced 16 B/lane
}

extern "C" void kernel_launch(void* const* d_in, const int* in_sizes, int n_in,
                              void* d_out, int out_size, void* d_ws, size_t ws_size,
                              hipStream_t stream) {
    const float4* x = (const float4*)d_in[0];
    const float*  w = (const float*)d_in[1];
    float4* out = (float4*)d_out;

    const int batch = in_sizes[0] / 4;   // x is (BATCH, 4) fp32
    const int block = 256;
    const int grid  = (batch + block - 1) / block;

    HilbertSimulator_12275016532163_kernel<<<grid, block, 0, stream>>>(x, w, out, batch);
}